// Round 1
// baseline (562.903 us; speedup 1.0000x reference)
//
#include <hip/hip_runtime.h>
#include <hip/hip_fp16.h>

#define N_NODES 100000
#define D 128
#define N_MESH 600000
#define N_WORLD 300000
#define BM 64          // nodes per block in MLP kernel
#define LDK 392        // padded leading dim of h tile (384 + 8) in bf16 elems
#define LDH 136        // padded leading dim of h1 tile (128 + 8)

typedef __attribute__((ext_vector_type(8))) short short8;
typedef __attribute__((ext_vector_type(4))) float f32x4;

// f32 -> bf16 round-to-nearest-even (finite inputs)
__device__ __forceinline__ unsigned short f2bf(float f) {
    unsigned u = __builtin_bit_cast(unsigned, f);
    u += 0x7fffu + ((u >> 16) & 1u);
    return (unsigned short)(u >> 16);
}

// packed 2xf16 global atomic add (gfx90a+ hw instruction, no return)
__device__ __forceinline__ void pk_add_f16(void* p, unsigned v) {
    asm volatile("global_atomic_pk_add_f16 %0, %1, off"
                 :: "v"((unsigned long long)(uintptr_t)p), "v"(v) : "memory");
}

// ---------------- scatter: agg[dst] += attr (f16 packed), cnt[dst] += 1 ----
__global__ __launch_bounds__(256) void scatter_pk(
        const float* __restrict__ attr, const int* __restrict__ dst, int E,
        __half* __restrict__ agg, int* __restrict__ cnt) {
    long long t = (long long)blockIdx.x * 256 + threadIdx.x;
    int e = (int)(t >> 5);            // 32 lanes per edge row
    if (e >= E) return;
    int lane = threadIdx.x & 31;
    int d = dst[e];
    const float4 v = *reinterpret_cast<const float4*>(&attr[(size_t)e * D + lane * 4]);
    unsigned p0 = __builtin_bit_cast(unsigned, __builtin_amdgcn_cvt_pkrtz(v.x, v.y));
    unsigned p1 = __builtin_bit_cast(unsigned, __builtin_amdgcn_cvt_pkrtz(v.z, v.w));
    __half* base = agg + ((size_t)d * D + lane * 4);
    pk_add_f16(base, p0);
    pk_add_f16(base + 2, p1);
    if (lane == 0) atomicAdd(&cnt[d], 1);
}

// ---------------- weight prep: transpose + f32->bf16 ----------------------
__global__ __launch_bounds__(256) void prep_weights(
        const float* __restrict__ W1, const float* __restrict__ W2,
        unsigned short* __restrict__ Wt1, unsigned short* __restrict__ Wt2) {
    int idx = blockIdx.x * 256 + threadIdx.x;
    if (idx < 384 * D) {
        int n = idx / 384, k = idx % 384;
        Wt1[n * 384 + k] = f2bf(W1[k * D + n]);      // Wt1[n][k] = W1[k][n]
    } else if (idx < 384 * D + D * D) {
        int i2 = idx - 384 * D;
        int n = i2 / D, k = i2 % D;
        Wt2[n * D + k] = f2bf(W2[k * D + n]);
    }
}

// ---------------- fused MLP per 64-node tile ------------------------------
__global__ __launch_bounds__(256) void mlp_kernel(
        const float* __restrict__ x,
        const __half* __restrict__ mesh_agg, const __half* __restrict__ world_agg,
        const int* __restrict__ mesh_cnt, const int* __restrict__ world_cnt,
        const unsigned short* __restrict__ Wt1, const unsigned short* __restrict__ Wt2,
        const float* __restrict__ b1, const float* __restrict__ b2,
        const float* __restrict__ gamma, const float* __restrict__ beta,
        float* __restrict__ out) {
    __shared__ __align__(16) short h_lds[BM * LDK];   // 50176 B, reused for h1
    const int tid = threadIdx.x;
    const int block0 = blockIdx.x * BM;

    // ---- Phase A: stage h = [x | mesh_agg/cnt | world_agg/cnt] as bf16 ----
    // x part
    for (int idx = tid; idx < BM * 32; idx += 256) {
        int row = idx >> 5, c4 = (idx & 31) * 4;
        int node = block0 + row;
        float4 v = {0.f, 0.f, 0.f, 0.f};
        if (node < N_NODES) v = *reinterpret_cast<const float4*>(&x[(size_t)node * D + c4]);
        ushort4 pack = {f2bf(v.x), f2bf(v.y), f2bf(v.z), f2bf(v.w)};
        *reinterpret_cast<ushort4*>(&h_lds[row * LDK + c4]) = pack;
    }
    // mesh part
    for (int idx = tid; idx < BM * 32; idx += 256) {
        int row = idx >> 5, c4 = (idx & 31) * 4;
        int node = block0 + row;
        float v0 = 0.f, v1 = 0.f, v2 = 0.f, v3 = 0.f;
        if (node < N_NODES) {
            int c = mesh_cnt[node];
            float inv = 1.0f / (float)(c > 1 ? c : 1);
            const __half2* p2 = reinterpret_cast<const __half2*>(&mesh_agg[(size_t)node * D + c4]);
            float2 f0 = __half22float2(p2[0]);
            float2 f1 = __half22float2(p2[1]);
            v0 = f0.x * inv; v1 = f0.y * inv; v2 = f1.x * inv; v3 = f1.y * inv;
        }
        ushort4 pack = {f2bf(v0), f2bf(v1), f2bf(v2), f2bf(v3)};
        *reinterpret_cast<ushort4*>(&h_lds[row * LDK + 128 + c4]) = pack;
    }
    // world part
    for (int idx = tid; idx < BM * 32; idx += 256) {
        int row = idx >> 5, c4 = (idx & 31) * 4;
        int node = block0 + row;
        float v0 = 0.f, v1 = 0.f, v2 = 0.f, v3 = 0.f;
        if (node < N_NODES) {
            int c = world_cnt[node];
            float inv = 1.0f / (float)(c > 1 ? c : 1);
            const __half2* p2 = reinterpret_cast<const __half2*>(&world_agg[(size_t)node * D + c4]);
            float2 f0 = __half22float2(p2[0]);
            float2 f1 = __half22float2(p2[1]);
            v0 = f0.x * inv; v1 = f0.y * inv; v2 = f1.x * inv; v3 = f1.y * inv;
        }
        ushort4 pack = {f2bf(v0), f2bf(v1), f2bf(v2), f2bf(v3)};
        *reinterpret_cast<ushort4*>(&h_lds[row * LDK + 256 + c4]) = pack;
    }
    __syncthreads();

    // ---- Phase B: GEMM1  h[64x384] @ W1[384x128]  (wave w owns 16 rows) --
    const int w = tid >> 6, l = tid & 63;
    const int lm = l & 15, lg = l >> 4;
    f32x4 acc[8];
    #pragma unroll
    for (int nt = 0; nt < 8; nt++) {
        float bv = b1[nt * 16 + lm];
        acc[nt] = (f32x4){bv, bv, bv, bv};
    }
    {
        const short* arow = &h_lds[(w * 16 + lm) * LDK + lg * 8];
        for (int ks = 0; ks < 12; ks++) {
            short8 a = *reinterpret_cast<const short8*>(arow + ks * 32);
            #pragma unroll
            for (int nt = 0; nt < 8; nt++) {
                short8 b = *reinterpret_cast<const short8*>(
                    &Wt1[(size_t)(nt * 16 + lm) * 384 + ks * 32 + lg * 8]);
                acc[nt] = __builtin_amdgcn_mfma_f32_16x16x32_bf16(a, b, acc[nt], 0, 0, 0);
            }
        }
    }
    __syncthreads();   // all waves finished reading h_lds

    // ---- Phase C: ReLU -> bf16 -> h1 in LDS (reuse h_lds) ----------------
    // C/D layout: col = nt*16 + (lane&15), row = (lane>>4)*4 + reg
    #pragma unroll
    for (int nt = 0; nt < 8; nt++) {
        #pragma unroll
        for (int r = 0; r < 4; r++) {
            float v = acc[nt][r] > 0.f ? acc[nt][r] : 0.f;
            int row = w * 16 + lg * 4 + r;
            h_lds[row * LDH + nt * 16 + lm] = (short)f2bf(v);
        }
    }
    __syncthreads();

    // ---- Phase D: GEMM2  h1[64x128] @ W2[128x128] ------------------------
    f32x4 acc2[8];
    #pragma unroll
    for (int nt = 0; nt < 8; nt++) {
        float bv = b2[nt * 16 + lm];
        acc2[nt] = (f32x4){bv, bv, bv, bv};
    }
    {
        const short* a2row = &h_lds[(w * 16 + lm) * LDH + lg * 8];
        for (int ks = 0; ks < 4; ks++) {
            short8 a = *reinterpret_cast<const short8*>(a2row + ks * 32);
            #pragma unroll
            for (int nt = 0; nt < 8; nt++) {
                short8 b = *reinterpret_cast<const short8*>(
                    &Wt2[(size_t)(nt * 16 + lm) * D + ks * 32 + lg * 8]);
                acc2[nt] = __builtin_amdgcn_mfma_f32_16x16x32_bf16(a, b, acc2[nt], 0, 0, 0);
            }
        }
    }

    // ---- Phase E: LayerNorm (in-register, 16-lane reductions) + residual -
    float gam[8], bet[8];
    #pragma unroll
    for (int nt = 0; nt < 8; nt++) {
        gam[nt] = gamma[nt * 16 + lm];
        bet[nt] = beta[nt * 16 + lm];
    }
    #pragma unroll
    for (int r = 0; r < 4; r++) {
        float s = 0.f, ss = 0.f;
        #pragma unroll
        for (int nt = 0; nt < 8; nt++) { float v = acc2[nt][r]; s += v; ss += v * v; }
        #pragma unroll
        for (int m = 1; m < 16; m <<= 1) {
            s  += __shfl_xor(s, m, 64);
            ss += __shfl_xor(ss, m, 64);
        }
        float mean = s * (1.0f / 128.0f);
        float var  = ss * (1.0f / 128.0f) - mean * mean;
        float rstd = rsqrtf(var + 1e-5f);
        int node = block0 + w * 16 + lg * 4 + r;
        if (node < N_NODES) {
            #pragma unroll
            for (int nt = 0; nt < 8; nt++) {
                int col = nt * 16 + lm;
                float v = (acc2[nt][r] - mean) * rstd * gam[nt] + bet[nt];
                out[(size_t)node * D + col] = x[(size_t)node * D + col] + v;
            }
        }
    }
}

extern "C" void kernel_launch(void* const* d_in, const int* in_sizes, int n_in,
                              void* d_out, int out_size, void* d_ws, size_t ws_size,
                              hipStream_t stream) {
    const float* x          = (const float*)d_in[0];
    const float* mesh_attr  = (const float*)d_in[1];
    const float* world_attr = (const float*)d_in[2];
    const int*   mesh_dst   = (const int*)d_in[3];
    const int*   world_dst  = (const int*)d_in[4];
    const float* W1         = (const float*)d_in[5];
    const float* b1         = (const float*)d_in[6];
    const float* W2         = (const float*)d_in[7];
    const float* b2         = (const float*)d_in[8];
    const float* gamma      = (const float*)d_in[9];
    const float* beta       = (const float*)d_in[10];
    float* out = (float*)d_out;

    char* ws = (char*)d_ws;
    size_t off = 0;
    __half* mesh_agg  = (__half*)(ws + off); off += (size_t)N_NODES * D * 2;
    __half* world_agg = (__half*)(ws + off); off += (size_t)N_NODES * D * 2;
    int* mesh_cnt  = (int*)(ws + off); off += (size_t)N_NODES * 4;
    int* world_cnt = (int*)(ws + off); off += (size_t)N_NODES * 4;
    size_t zero_bytes = off;
    unsigned short* Wt1 = (unsigned short*)(ws + off); off += (size_t)384 * D * 2;
    unsigned short* Wt2 = (unsigned short*)(ws + off); off += (size_t)D * D * 2;

    hipMemsetAsync(d_ws, 0, zero_bytes, stream);
    prep_weights<<<(384 * D + D * D + 255) / 256, 256, 0, stream>>>(W1, W2, Wt1, Wt2);
    scatter_pk<<<(N_MESH  * 32 + 255) / 256, 256, 0, stream>>>(mesh_attr,  mesh_dst,  N_MESH,  mesh_agg,  mesh_cnt);
    scatter_pk<<<(N_WORLD * 32 + 255) / 256, 256, 0, stream>>>(world_attr, world_dst, N_WORLD, world_agg, world_cnt);
    mlp_kernel<<<(N_NODES + BM - 1) / BM, 256, 0, stream>>>(
        x, mesh_agg, world_agg, mesh_cnt, world_cnt,
        Wt1, Wt2, b1, b2, gamma, beta, out);
}